// Round 4
// baseline (1277.607 us; speedup 1.0000x reference)
//
#include <hip/hip_runtime.h>
#include <hip/hip_bf16.h>
#include <math.h>

// Problem constants
#define B_   4
#define S_   2048
#define D_   2048
#define H_   16
#define HD_  128
#define N3_  6144   // 3*D
#define M_   8192   // B*S

typedef __attribute__((ext_vector_type(8))) short  short8;
typedef __attribute__((ext_vector_type(4))) float  float4_;

using bf16 = __hip_bfloat16;

static __device__ __forceinline__ float bf2f(bf16 v){ return __bfloat162float(v); }
static __device__ __forceinline__ bf16  f2bf(float v){ return __float2bfloat16(v); }
static __device__ __forceinline__ short f2bfs(float v){
    return (short)__builtin_bit_cast(unsigned short, __float2bfloat16(v));
}

// load 8 elements as bf16 short8 — overloaded on source dtype
static __device__ __forceinline__ short8 load8(const bf16* p){ return *(const short8*)p; }
static __device__ __forceinline__ short8 load8(const float* p){
    float4_ a = *(const float4_*)p;
    float4_ b = *(const float4_*)(p + 4);
    short8 r;
    r[0]=f2bfs(a[0]); r[1]=f2bfs(a[1]); r[2]=f2bfs(a[2]); r[3]=f2bfs(a[3]);
    r[4]=f2bfs(b[0]); r[5]=f2bfs(b[1]); r[6]=f2bfs(b[2]); r[7]=f2bfs(b[3]);
    return r;
}

// ---------------- cast fp32 -> bf16 (fast path only) ----------------
__global__ void cast_f32_bf16(const float* __restrict__ in, bf16* __restrict__ out, long n8){
    long i = (long)blockIdx.x * blockDim.x + threadIdx.x;
    if (i >= n8) return;
    *((short8*)out + i) = load8(in + 8*i);
}

// ---------------- bf16 MFMA GEMM: C = A * Bt^T + bias ----------------
// A: (M,K) row-major, lda stride; Bt: (N,K) row-major, ldb stride; bias fp32 (N)
// fp32 inputs converted to bf16 during LDS staging. 128x128 tile, BK=32,
// 4 waves (2x2), 64x64/wave, 16x16x32 MFMA.
template<typename AT, typename BT, typename OUT_T>
__global__ __launch_bounds__(256) void gemm_bt(const AT* __restrict__ A, int lda,
                                               const BT* __restrict__ Bt, int ldb,
                                               const float* __restrict__ bias,
                                               OUT_T* __restrict__ C, int ldc, int Kdim){
    __shared__ __align__(16) bf16 As[128*32];
    __shared__ __align__(16) bf16 Bs[128*32];
    const int tid  = threadIdx.x;
    const int lane = tid & 63;
    const int w    = tid >> 6;
    const int wm   = w >> 1, wn = w & 1;
    const int quad = lane >> 4, l15 = lane & 15;
    const int bn0  = blockIdx.x * 128, bm0 = blockIdx.y * 128;
    const int srow = tid >> 2;          // 0..63
    const int scol = (tid & 3) * 8;     // 0,8,16,24

    float4_ acc[4][4] = {};

    for (int k0 = 0; k0 < Kdim; k0 += 32){
        __syncthreads();
        #pragma unroll
        for (int half = 0; half < 2; ++half){
            int r = half*64 + srow;
            *(short8*)&As[r*32 + scol] = load8(&A[(size_t)(bm0 + r)*lda + k0 + scol]);
            *(short8*)&Bs[r*32 + scol] = load8(&Bt[(size_t)(bn0 + r)*ldb + k0 + scol]);
        }
        __syncthreads();
        short8 af[4], bfr[4];
        #pragma unroll
        for (int mt = 0; mt < 4; ++mt) af[mt]  = *(const short8*)&As[(wm*64 + mt*16 + l15)*32 + quad*8];
        #pragma unroll
        for (int nt = 0; nt < 4; ++nt) bfr[nt] = *(const short8*)&Bs[(wn*64 + nt*16 + l15)*32 + quad*8];
        #pragma unroll
        for (int mt = 0; mt < 4; ++mt)
            #pragma unroll
            for (int nt = 0; nt < 4; ++nt)
                acc[mt][nt] = __builtin_amdgcn_mfma_f32_16x16x32_bf16(af[mt], bfr[nt], acc[mt][nt], 0, 0, 0);
    }

    // epilogue: C/D layout col=lane&15, row=quad*4+reg (m89/m91 verified)
    #pragma unroll
    for (int mt = 0; mt < 4; ++mt){
        int row = bm0 + wm*64 + mt*16 + quad*4;
        #pragma unroll
        for (int nt = 0; nt < 4; ++nt){
            int col = bn0 + wn*64 + nt*16 + l15;
            float bia = bias[col];
            #pragma unroll
            for (int r = 0; r < 4; ++r){
                float v = acc[mt][nt][r] + bia;
                size_t idx = (size_t)(row + r)*ldc + col;
                if constexpr (sizeof(OUT_T) == 2) ((bf16*)C)[idx] = f2bf(v);
                else                              ((float*)C)[idx] = v;
            }
        }
    }
}

// ---------------- RoPE apply in-place on q,k inside qkv (inline trig) --------
__global__ void rope_apply(bf16* __restrict__ qkv){
    int idx = blockIdx.x * blockDim.x + threadIdx.x;  // ((b*S+s)*H + h)*64 + p
    int p = idx & 63;
    int h = (idx >> 6) & (H_-1);
    int s = (idx >> 10) & (S_-1);
    int b = idx >> 21;
    float freq = powf(10000.0f, -(float)(2*p) / (float)HD_);
    float ang = (float)s * freq;
    float c = cosf(ang), sn = sinf(ang);
    size_t base = (size_t)(b*S_ + s) * N3_ + h*HD_ + 2*p;
    // q
    float tr = bf2f(qkv[base]), ti = bf2f(qkv[base+1]);
    qkv[base]   = f2bf(tr*c - ti*sn);
    qkv[base+1] = f2bf(tr*sn + ti*c);
    // k
    size_t kb = base + D_;
    tr = bf2f(qkv[kb]); ti = bf2f(qkv[kb+1]);
    qkv[kb]   = f2bf(tr*c - ti*sn);
    qkv[kb+1] = f2bf(tr*sn + ti*c);
}

// ---------------- causal flash attention ----------------
// 1 wave/block; 16 q-rows; 32-key chunks; MFMA 16x16x32.
// Q,K,V read in-place from qkv (B,S,3D); O written into the q-slice
// (race-free: only this block ever touches its own q rows x head cols,
//  and Q is register-resident before the first O write).
#define VS_STRIDE 136   // 272 B rows: 16B-aligned; scalar-read banks = 4-way (1.58x, ok)
__global__ __launch_bounds__(64) void attn(bf16* __restrict__ QKV){
    int t = blockIdx.x, bh = blockIdx.y;
    int b = bh >> 4, h = bh & 15;
    int lane = threadIdx.x, quad = lane >> 4, l15 = lane & 15;
    bf16* Qp = QKV + (size_t)b*S_*N3_ + h*HD_;
    const bf16* Kp = Qp + D_;
    const bf16* Vp = Qp + 2*D_;
    __shared__ __align__(16) bf16 Pls[16*32];
    __shared__ __align__(16) bf16 Vs[32*VS_STRIDE];

    short8 qf[4];
    int qrow = t*16 + l15;
    #pragma unroll
    for (int kc = 0; kc < 4; ++kc)
        qf[kc] = *(const short8*)&Qp[(size_t)qrow*N3_ + kc*32 + quad*8];

    float4_ accO[8] = {};
    float m_i[4], l_i[4];
    #pragma unroll
    for (int r = 0; r < 4; ++r){ m_i[r] = -3.0e38f; l_i[r] = 0.0f; }
    const float scale = 0.088388347648318447f;  // 1/sqrt(128)

    const int vrow = lane >> 1;         // 0..31
    const int vcol = (lane & 1) * 64;   // 0 or 64

    int nch = (16*t + 47) >> 5;
    for (int c = 0; c < nch; ++c){
        int kb = c * 32;
        __syncthreads();   // protect Vs/Pls reuse across iterations (WAR)
        // stage V chunk (32 keys x 128 d) row-major into LDS
        #pragma unroll
        for (int j = 0; j < 8; ++j)
            *(short8*)&Vs[vrow*VS_STRIDE + vcol + j*8] =
                *(const short8*)&Vp[(size_t)(kb + vrow)*N3_ + vcol + j*8];

        float4_ sacc[2] = {};
        #pragma unroll
        for (int nt = 0; nt < 2; ++nt)
            #pragma unroll
            for (int kc = 0; kc < 4; ++kc){
                short8 kf = *(const short8*)&Kp[(size_t)(kb + nt*16 + l15)*N3_ + kc*32 + quad*8];
                sacc[nt] = __builtin_amdgcn_mfma_f32_16x16x32_bf16(qf[kc], kf, sacc[nt], 0, 0, 0);
            }

        // scale + causal mask (C layout: col=l15 -> key j, row=quad*4+r -> query)
        float sv[2][4];
        int rbase = t*16 + quad*4;
        #pragma unroll
        for (int nt = 0; nt < 2; ++nt){
            int j = kb + nt*16 + l15;
            #pragma unroll
            for (int r = 0; r < 4; ++r){
                float v = sacc[nt][r] * scale;
                sv[nt][r] = (j > rbase + r) ? -3.0e38f : v;
            }
        }
        // online softmax (row reductions across 16 lanes)
        float nm[4], alpha[4];
        #pragma unroll
        for (int r = 0; r < 4; ++r){
            float v = fmaxf(fmaxf(sv[0][r], sv[1][r]), m_i[r]);
            #pragma unroll
            for (int off = 1; off < 16; off <<= 1) v = fmaxf(v, __shfl_xor(v, off, 64));
            nm[r] = v;
        }
        #pragma unroll
        for (int r = 0; r < 4; ++r){
            alpha[r] = expf(m_i[r] - nm[r]);
            float p0 = expf(sv[0][r] - nm[r]);
            float p1 = expf(sv[1][r] - nm[r]);
            sv[0][r] = p0; sv[1][r] = p1;
            float s = p0 + p1;
            #pragma unroll
            for (int off = 1; off < 16; off <<= 1) s += __shfl_xor(s, off, 64);
            l_i[r] = l_i[r]*alpha[r] + s;
            m_i[r] = nm[r];
        }
        #pragma unroll
        for (int dt = 0; dt < 8; ++dt)
            #pragma unroll
            for (int r = 0; r < 4; ++r) accO[dt][r] *= alpha[r];

        // P: C-layout -> LDS -> A-layout (m120 pattern)
        #pragma unroll
        for (int nt = 0; nt < 2; ++nt)
            #pragma unroll
            for (int r = 0; r < 4; ++r)
                Pls[(quad*4 + r)*32 + nt*16 + l15] = f2bf(sv[nt][r]);
        __syncthreads();
        short8 pf = *(const short8*)&Pls[l15*32 + quad*8];

        // PV: B-fragment vf[j] = V^T[d][k] = Vs[key=quad*8+j][d=dt*16+l15]
        #pragma unroll
        for (int dt = 0; dt < 8; ++dt){
            short8 vf;
            #pragma unroll
            for (int j = 0; j < 8; ++j)
                vf[j] = (short)__builtin_bit_cast(unsigned short,
                            Vs[(quad*8 + j)*VS_STRIDE + dt*16 + l15]);
            accO[dt] = __builtin_amdgcn_mfma_f32_16x16x32_bf16(pf, vf, accO[dt], 0, 0, 0);
        }
    }

    float inv[4];
    #pragma unroll
    for (int r = 0; r < 4; ++r) inv[r] = 1.0f / l_i[r];
    // O into q-slice: addr = Qp[s*N3 + d]
    #pragma unroll
    for (int dt = 0; dt < 8; ++dt)
        #pragma unroll
        for (int r = 0; r < 4; ++r){
            int s = t*16 + quad*4 + r;
            int d = dt*16 + l15;
            Qp[(size_t)s*N3_ + d] = f2bf(accO[dt][r]*inv[r]);
        }
}

// ---------------- launch ----------------
extern "C" void kernel_launch(void* const* d_in, const int* in_sizes, int n_in,
                              void* d_out, int out_size, void* d_ws, size_t ws_size,
                              hipStream_t stream){
    const float* x    = (const float*)d_in[0];
    const float* Wqkv = (const float*)d_in[1];
    const float* bqkv = (const float*)d_in[2];
    const float* Wo   = (const float*)d_in[3];
    const float* bo   = (const float*)d_in[4];
    float* out = (float*)d_out;
    char* ws = (char*)d_ws;

    // qkv is the only mandatory buffer: 8192 x 6144 bf16 = 100,663,296 B (96 MiB)
    bf16* qkv = (bf16*)(ws + 0);

    // Fast path needs additionally: xb 32 MiB + wqkvb 24 MiB + wob 8 MiB -> 160 MiB total
    const size_t OFF_XB = 100663296, OFF_WQ = 134217728, OFF_WO = 159383552;
    const bool big = (ws_size >= (size_t)167772160);

    if (big){
        bf16* xb    = (bf16*)(ws + OFF_XB);
        bf16* wqkvb = (bf16*)(ws + OFF_WQ);
        bf16* wob   = (bf16*)(ws + OFF_WO);
        long n8;
        n8 = (long)M_*D_/8;   cast_f32_bf16<<<(n8+255)/256, 256, 0, stream>>>(x, xb, n8);
        n8 = (long)N3_*D_/8;  cast_f32_bf16<<<(n8+255)/256, 256, 0, stream>>>(Wqkv, wqkvb, n8);
        n8 = (long)D_*D_/8;   cast_f32_bf16<<<(n8+255)/256, 256, 0, stream>>>(Wo, wob, n8);
        gemm_bt<bf16,bf16,bf16><<<dim3(N3_/128, M_/128), 256, 0, stream>>>(
            xb, D_, wqkvb, D_, bqkv, qkv, N3_, D_);
        rope_apply<<<(B_*S_*H_*64)/256, 256, 0, stream>>>(qkv);
        attn<<<dim3(S_/16, B_*H_), 64, 0, stream>>>(qkv);
        gemm_bt<bf16,bf16,float><<<dim3(D_/128, M_/128), 256, 0, stream>>>(
            qkv, N3_, wob, D_, bo, out, D_, D_);
    } else {
        // compact path: fp32 inputs converted during GEMM staging; 96 MiB workspace
        gemm_bt<float,float,bf16><<<dim3(N3_/128, M_/128), 256, 0, stream>>>(
            x, D_, Wqkv, D_, bqkv, qkv, N3_, D_);
        rope_apply<<<(B_*S_*H_*64)/256, 256, 0, stream>>>(qkv);
        attn<<<dim3(S_/16, B_*H_), 64, 0, stream>>>(qkv);
        gemm_bt<bf16,float,float><<<dim3(D_/128, M_/128), 256, 0, stream>>>(
            qkv, N3_, Wo, D_, bo, out, D_, D_);
    }
}

// Round 5
// 1043.201 us; speedup vs baseline: 1.2247x; 1.2247x over previous
//
#include <hip/hip_runtime.h>
#include <hip/hip_bf16.h>
#include <math.h>

// Problem constants
#define B_   4
#define S_   2048
#define D_   2048
#define H_   16
#define HD_  128
#define N3_  6144   // 3*D
#define M_   8192   // B*S

typedef __attribute__((ext_vector_type(8))) short  short8;
typedef __attribute__((ext_vector_type(4))) float  float4_;

using bf16 = __hip_bfloat16;

static __device__ __forceinline__ float bf2f(bf16 v){ return __bfloat162float(v); }
static __device__ __forceinline__ bf16  f2bf(float v){ return __float2bfloat16(v); }
static __device__ __forceinline__ short f2bfs(float v){
    return (short)__builtin_bit_cast(unsigned short, __float2bfloat16(v));
}

// load 8 elements as bf16 short8 — overloaded on source dtype
static __device__ __forceinline__ short8 load8(const bf16* p){ return *(const short8*)p; }
static __device__ __forceinline__ short8 load8(const float* p){
    float4_ a = *(const float4_*)p;
    float4_ b = *(const float4_*)(p + 4);
    short8 r;
    r[0]=f2bfs(a[0]); r[1]=f2bfs(a[1]); r[2]=f2bfs(a[2]); r[3]=f2bfs(a[3]);
    r[4]=f2bfs(b[0]); r[5]=f2bfs(b[1]); r[6]=f2bfs(b[2]); r[7]=f2bfs(b[3]);
    return r;
}

// ---------------- cast fp32 -> bf16 (fast path only) ----------------
__global__ void cast_f32_bf16(const float* __restrict__ in, bf16* __restrict__ out, long n8){
    long i = (long)blockIdx.x * blockDim.x + threadIdx.x;
    if (i >= n8) return;
    *((short8*)out + i) = load8(in + 8*i);
}

// ---------------- bf16 MFMA GEMM: C = A * Bt^T + bias ----------------
template<typename AT, typename BT, typename OUT_T>
__global__ __launch_bounds__(256) void gemm_bt(const AT* __restrict__ A, int lda,
                                               const BT* __restrict__ Bt, int ldb,
                                               const float* __restrict__ bias,
                                               OUT_T* __restrict__ C, int ldc, int Kdim){
    __shared__ __align__(16) bf16 As[128*32];
    __shared__ __align__(16) bf16 Bs[128*32];
    const int tid  = threadIdx.x;
    const int lane = tid & 63;
    const int w    = tid >> 6;
    const int wm   = w >> 1, wn = w & 1;
    const int quad = lane >> 4, l15 = lane & 15;
    const int bn0  = blockIdx.x * 128, bm0 = blockIdx.y * 128;
    const int srow = tid >> 2;          // 0..63
    const int scol = (tid & 3) * 8;     // 0,8,16,24

    float4_ acc[4][4] = {};

    for (int k0 = 0; k0 < Kdim; k0 += 32){
        __syncthreads();
        #pragma unroll
        for (int half = 0; half < 2; ++half){
            int r = half*64 + srow;
            *(short8*)&As[r*32 + scol] = load8(&A[(size_t)(bm0 + r)*lda + k0 + scol]);
            *(short8*)&Bs[r*32 + scol] = load8(&Bt[(size_t)(bn0 + r)*ldb + k0 + scol]);
        }
        __syncthreads();
        short8 af[4], bfr[4];
        #pragma unroll
        for (int mt = 0; mt < 4; ++mt) af[mt]  = *(const short8*)&As[(wm*64 + mt*16 + l15)*32 + quad*8];
        #pragma unroll
        for (int nt = 0; nt < 4; ++nt) bfr[nt] = *(const short8*)&Bs[(wn*64 + nt*16 + l15)*32 + quad*8];
        #pragma unroll
        for (int mt = 0; mt < 4; ++mt)
            #pragma unroll
            for (int nt = 0; nt < 4; ++nt)
                acc[mt][nt] = __builtin_amdgcn_mfma_f32_16x16x32_bf16(af[mt], bfr[nt], acc[mt][nt], 0, 0, 0);
    }

    // epilogue: C/D layout col=lane&15, row=quad*4+reg (m89/m91 verified)
    #pragma unroll
    for (int mt = 0; mt < 4; ++mt){
        int row = bm0 + wm*64 + mt*16 + quad*4;
        #pragma unroll
        for (int nt = 0; nt < 4; ++nt){
            int col = bn0 + wn*64 + nt*16 + l15;
            float bia = bias[col];
            #pragma unroll
            for (int r = 0; r < 4; ++r){
                float v = acc[mt][nt][r] + bia;
                size_t idx = (size_t)(row + r)*ldc + col;
                if constexpr (sizeof(OUT_T) == 2) ((bf16*)C)[idx] = f2bf(v);
                else                              ((float*)C)[idx] = v;
            }
        }
    }
}

// ---------------- RoPE apply in-place on q,k inside qkv (inline trig) --------
__global__ void rope_apply(bf16* __restrict__ qkv){
    int idx = blockIdx.x * blockDim.x + threadIdx.x;  // ((b*S+s)*H + h)*64 + p
    int p = idx & 63;
    int h = (idx >> 6) & (H_-1);
    int s = (idx >> 10) & (S_-1);
    int b = idx >> 21;
    float freq = powf(10000.0f, -(float)(2*p) / (float)HD_);
    float ang = (float)s * freq;
    float c = cosf(ang), sn = sinf(ang);
    size_t base = (size_t)(b*S_ + s) * N3_ + h*HD_ + 2*p;
    float tr = bf2f(qkv[base]), ti = bf2f(qkv[base+1]);
    qkv[base]   = f2bf(tr*c - ti*sn);
    qkv[base+1] = f2bf(tr*sn + ti*c);
    size_t kb = base + D_;
    tr = bf2f(qkv[kb]); ti = bf2f(qkv[kb+1]);
    qkv[kb]   = f2bf(tr*c - ti*sn);
    qkv[kb+1] = f2bf(tr*sn + ti*c);
}

// ---------------- causal flash attention (4-wave blocks, LDS-shared K/V) -----
// Block = 256 threads (4 waves), 64 q-rows/block (wave w owns rows t*64+w*16..+15).
// K chunk (32x128, stride 136: conflict-free b128 frag reads) and V chunk
// transposed (Vt[d][key], stride 40, XOR group-swizzle: conflict-free b128 frag
// reads, 2-way-free u16 transpose writes) staged cooperatively per chunk.
// O written into the q-slice of qkv (race-free; Q is register-resident first).
#define KS_STRIDE 136
#define VT_STRIDE 40
__global__ __launch_bounds__(256) void attn(bf16* __restrict__ QKV){
    const int t = blockIdx.x, bh = blockIdx.y;
    const int b = bh >> 4, h = bh & 15;
    const int tid = threadIdx.x;
    const int w = tid >> 6, lane = tid & 63, quad = lane >> 4, l15 = lane & 15;
    bf16* Qp = QKV + (size_t)b*S_*N3_ + h*HD_;
    const bf16* Kp = Qp + D_;
    const bf16* Vp = Qp + 2*D_;
    __shared__ __align__(16) bf16 Ks[32*KS_STRIDE];
    __shared__ __align__(16) bf16 Vt[128*VT_STRIDE];
    __shared__ __align__(16) bf16 Pls[4*16*32];

    // staging ids: 8 lanes cover one key's 128 d (coalesced 256B), 32 keys/block
    const int skey = tid >> 3;          // 0..31
    const int sd   = (tid & 7) * 16;    // 0,16,...,112
    const int sg   = ((sd >> 4) & 3) << 3;   // V swizzle group offset
    const int kpos = skey ^ sg;

    // Q fragments (register-resident)
    const int qrow = t*64 + w*16 + l15;
    short8 qf[4];
    #pragma unroll
    for (int kc = 0; kc < 4; ++kc)
        qf[kc] = *(const short8*)&Qp[(size_t)qrow*N3_ + kc*32 + quad*8];

    float4_ accO[8] = {};
    float m_i[4], l_i[4];
    #pragma unroll
    for (int r = 0; r < 4; ++r){ m_i[r] = -3.0e38f; l_i[r] = 0.0f; }
    const float scale = 0.088388347648318447f;  // 1/sqrt(128)
    const int rbase = t*64 + w*16 + quad*4;
    const int wmax  = t*64 + w*16 + 15;   // wave's last q row

    const int nch = 2*t + 2;
    for (int c = 0; c < nch; ++c){
        const int kb = c * 32;
        __syncthreads();   // all compute reads of previous chunk done (WAR)
        // ---- stage K (vectorized) + V (transposed, swizzled) ----
        {
            const bf16* krow = &Kp[(size_t)(kb + skey)*N3_];
            *(short8*)&Ks[skey*KS_STRIDE + sd]     = *(const short8*)&krow[sd];
            *(short8*)&Ks[skey*KS_STRIDE + sd + 8] = *(const short8*)&krow[sd + 8];
            const bf16* vrow = &Vp[(size_t)(kb + skey)*N3_];
            short8 v0 = *(const short8*)&vrow[sd];
            short8 v1 = *(const short8*)&vrow[sd + 8];
            #pragma unroll
            for (int j = 0; j < 8; ++j){
                Vt[(sd + j)*VT_STRIDE + kpos]     = __builtin_bit_cast(bf16, (unsigned short)v0[j]);
                Vt[(sd + 8 + j)*VT_STRIDE + kpos] = __builtin_bit_cast(bf16, (unsigned short)v1[j]);
            }
        }
        __syncthreads();

        if (kb <= wmax){   // wave-uniform: skip fully-masked chunks
            // ---- QK^T ----
            float4_ sacc[2] = {};
            #pragma unroll
            for (int nt = 0; nt < 2; ++nt)
                #pragma unroll
                for (int kc = 0; kc < 4; ++kc){
                    short8 kf = *(const short8*)&Ks[(nt*16 + l15)*KS_STRIDE + kc*32 + quad*8];
                    sacc[nt] = __builtin_amdgcn_mfma_f32_16x16x32_bf16(qf[kc], kf, sacc[nt], 0, 0, 0);
                }

            // ---- scale + causal mask ----
            float sv[2][4];
            #pragma unroll
            for (int nt = 0; nt < 2; ++nt){
                int j = kb + nt*16 + l15;
                #pragma unroll
                for (int r = 0; r < 4; ++r){
                    float v = sacc[nt][r] * scale;
                    sv[nt][r] = (j > rbase + r) ? -3.0e38f : v;
                }
            }
            // ---- online softmax (reduce across 16 lanes) ----
            float nm[4], alpha[4];
            #pragma unroll
            for (int r = 0; r < 4; ++r){
                float v = fmaxf(fmaxf(sv[0][r], sv[1][r]), m_i[r]);
                #pragma unroll
                for (int off = 1; off < 16; off <<= 1) v = fmaxf(v, __shfl_xor(v, off, 64));
                nm[r] = v;
            }
            #pragma unroll
            for (int r = 0; r < 4; ++r){
                alpha[r] = __expf(m_i[r] - nm[r]);
                float p0 = __expf(sv[0][r] - nm[r]);
                float p1 = __expf(sv[1][r] - nm[r]);
                sv[0][r] = p0; sv[1][r] = p1;
                float s = p0 + p1;
                #pragma unroll
                for (int off = 1; off < 16; off <<= 1) s += __shfl_xor(s, off, 64);
                l_i[r] = l_i[r]*alpha[r] + s;
                m_i[r] = nm[r];
            }
            #pragma unroll
            for (int dt = 0; dt < 8; ++dt)
                #pragma unroll
                for (int r = 0; r < 4; ++r) accO[dt][r] *= alpha[r];

            // ---- P: C-layout -> per-wave LDS -> A-layout (wave-local fence) ----
            #pragma unroll
            for (int nt = 0; nt < 2; ++nt)
                #pragma unroll
                for (int r = 0; r < 4; ++r)
                    Pls[w*512 + (quad*4 + r)*32 + nt*16 + l15] = f2bf(sv[nt][r]);
            __asm volatile("s_waitcnt lgkmcnt(0)" ::: "memory");
            short8 pf = *(const short8*)&Pls[w*512 + l15*32 + quad*8];

            // ---- PV (Vt swizzled: group quad^g, g = dt&3) ----
            #pragma unroll
            for (int dt = 0; dt < 8; ++dt){
                const int g = dt & 3;
                short8 vf = *(const short8*)&Vt[(dt*16 + l15)*VT_STRIDE + ((quad ^ g)*8)];
                accO[dt] = __builtin_amdgcn_mfma_f32_16x16x32_bf16(pf, vf, accO[dt], 0, 0, 0);
            }
        }
    }

    float inv[4];
    #pragma unroll
    for (int r = 0; r < 4; ++r) inv[r] = 1.0f / l_i[r];
    #pragma unroll
    for (int dt = 0; dt < 8; ++dt)
        #pragma unroll
        for (int r = 0; r < 4; ++r){
            int s = t*64 + w*16 + quad*4 + r;
            int d = dt*16 + l15;
            Qp[(size_t)s*N3_ + d] = f2bf(accO[dt][r]*inv[r]);
        }
}

// ---------------- launch ----------------
extern "C" void kernel_launch(void* const* d_in, const int* in_sizes, int n_in,
                              void* d_out, int out_size, void* d_ws, size_t ws_size,
                              hipStream_t stream){
    const float* x    = (const float*)d_in[0];
    const float* Wqkv = (const float*)d_in[1];
    const float* bqkv = (const float*)d_in[2];
    const float* Wo   = (const float*)d_in[3];
    const float* bo   = (const float*)d_in[4];
    float* out = (float*)d_out;
    char* ws = (char*)d_ws;

    // qkv is the only mandatory buffer: 8192 x 6144 bf16 = 100,663,296 B (96 MiB)
    bf16* qkv = (bf16*)(ws + 0);

    // Fast path needs additionally: xb 32 MiB + wqkvb 24 MiB + wob 8 MiB -> 160 MiB total
    const size_t OFF_XB = 100663296, OFF_WQ = 134217728, OFF_WO = 159383552;
    const bool big = (ws_size >= (size_t)167772160);

    if (big){
        bf16* xb    = (bf16*)(ws + OFF_XB);
        bf16* wqkvb = (bf16*)(ws + OFF_WQ);
        bf16* wob   = (bf16*)(ws + OFF_WO);
        long n8;
        n8 = (long)M_*D_/8;   cast_f32_bf16<<<(n8+255)/256, 256, 0, stream>>>(x, xb, n8);
        n8 = (long)N3_*D_/8;  cast_f32_bf16<<<(n8+255)/256, 256, 0, stream>>>(Wqkv, wqkvb, n8);
        n8 = (long)D_*D_/8;   cast_f32_bf16<<<(n8+255)/256, 256, 0, stream>>>(Wo, wob, n8);
        gemm_bt<bf16,bf16,bf16><<<dim3(N3_/128, M_/128), 256, 0, stream>>>(
            xb, D_, wqkvb, D_, bqkv, qkv, N3_, D_);
        rope_apply<<<(B_*S_*H_*64)/256, 256, 0, stream>>>(qkv);
        attn<<<dim3(S_/64, B_*H_), 256, 0, stream>>>(qkv);
        gemm_bt<bf16,bf16,float><<<dim3(D_/128, M_/128), 256, 0, stream>>>(
            qkv, N3_, wob, D_, bo, out, D_, D_);
    } else {
        // compact path: fp32 inputs converted during GEMM staging; 96 MiB workspace
        gemm_bt<float,float,bf16><<<dim3(N3_/128, M_/128), 256, 0, stream>>>(
            x, D_, Wqkv, D_, bqkv, qkv, N3_, D_);
        rope_apply<<<(B_*S_*H_*64)/256, 256, 0, stream>>>(qkv);
        attn<<<dim3(S_/64, B_*H_), 256, 0, stream>>>(qkv);
        gemm_bt<bf16,float,float><<<dim3(D_/128, M_/128), 256, 0, stream>>>(
            qkv, N3_, Wo, D_, bo, out, D_, D_);
    }
}